// Round 3
// baseline (5786.821 us; speedup 1.0000x reference)
//
#include <hip/hip_runtime.h>
#include <hip/hip_bf16.h>
#include <math.h>

#define IN_DIM 128
#define PRE_HID 256
#define HID 16

__device__ __forceinline__ float lrelu(float v) { return v > 0.f ? v : 0.01f * v; }
__device__ __forceinline__ float fin(float v) { return (v == v && fabsf(v) < 1e30f) ? v : 0.f; }

// generic element load: fp32 or bf16 per flag
__device__ __forceinline__ float ldp(const void* p, size_t i, int f32) {
    if (f32) return ((const float*)p)[i];
    unsigned u = ((const unsigned short*)p)[i];
    return __uint_as_float(u << 16);
}
__device__ __forceinline__ unsigned short f2bf(float f) {
    union { __hip_bfloat16 b; unsigned short u; } cv;
    cv.b = __float2bfloat16(f);
    return cv.u;
}
__device__ __forceinline__ void unpack8(uint4 u, float* o) {
    o[0] = __uint_as_float(u.x << 16); o[1] = __uint_as_float(u.x & 0xFFFF0000u);
    o[2] = __uint_as_float(u.y << 16); o[3] = __uint_as_float(u.y & 0xFFFF0000u);
    o[4] = __uint_as_float(u.z << 16); o[5] = __uint_as_float(u.z & 0xFFFF0000u);
    o[6] = __uint_as_float(u.w << 16); o[7] = __uint_as_float(u.w & 0xFFFF0000u);
}
__device__ __forceinline__ unsigned pk2(float a, float b) {
    return (unsigned)f2bf(a) | ((unsigned)f2bf(b) << 16);
}
__device__ __forceinline__ uint4 pack8(const float* v) {
    uint4 u;
    u.x = pk2(v[0], v[1]); u.y = pk2(v[2], v[3]);
    u.z = pk2(v[4], v[5]); u.w = pk2(v[6], v[7]);
    return u;
}

// ---- fixed small-param region (float offsets); N-dependent regions computed at launch
#define OFF_W1F   0          // fp32 [32768]
#define OFF_B1F   32768      // fp32 [256]
#define OFF_W2T   33024      // fp32 [4096]
#define OFF_B2F   37120      // fp32 [16]
#define OFF_HW    37136      // fp32 [2][256]
#define OFF_GCNB  37648      // fp32 [2][16]
#define OFF_POST  37680      // fp32 [34] (+pad)
#define OFF_FLAGS 37720      // int [2]: [0]=int64 edges, [1]=fp32 floats
#define OFF_END   37760

// ---------------- dtype detection ----------------
__global__ void k_detect(const unsigned short* __restrict__ xu,
                         const int* __restrict__ ei32, int* __restrict__ flags) {
    if (threadIdx.x == 0 && blockIdx.x == 0) {
        int band = 0;
        for (int k = 0; k < 128; ++k) {
            unsigned e = (xu[2 * k] >> 7) & 0xFF;  // exponent byte of even bf16 slot
            if (e >= 100 && e <= 140) band++;
        }
        flags[1] = (band < 96) ? 1 : 0;  // low in-band count => fp32 data
        int any = 0;
        for (int k = 0; k < 64; ++k) any |= ei32[2 * k + 1];
        flags[0] = (any == 0) ? 1 : 0;   // all-zero odd slots => int64
    }
}

__global__ void k_sentinel(unsigned* __restrict__ out, int words, unsigned val) {
    int i = blockIdx.x * 256 + threadIdx.x;
    if (i < words) out[i] = val;
}

// ---------------- small params ----------------
__global__ void k_prep_small(const void* __restrict__ bih, const void* __restrict__ bhh,
                             const void* __restrict__ wtW, const void* __restrict__ wtb,
                             const void* __restrict__ p1W, const void* __restrict__ p1b,
                             const void* __restrict__ paW, const void* __restrict__ pab,
                             const int* __restrict__ flags,
                             float* __restrict__ hw, float* __restrict__ post) {
    int f32 = flags[1];
    __shared__ float mem[2][16];
    int t = threadIdx.x;
    if (t < 32) {
        int l = t >> 4, j = t & 15;
        float bi0 = ldp(bih, l * 48 + j, f32),      bh0 = ldp(bhh, l * 48 + j, f32);
        float bi1 = ldp(bih, l * 48 + 16 + j, f32), bh1 = ldp(bhh, l * 48 + 16 + j, f32);
        float bi2 = ldp(bih, l * 48 + 32 + j, f32), bh2 = ldp(bhh, l * 48 + 32 + j, f32);
        float r = 1.f / (1.f + expf(-(bi0 + bh0)));
        float z = 1.f / (1.f + expf(-(bi1 + bh1)));
        float nn = tanhf(bi2 + r * bh2);
        mem[l][j] = (1.f - z) * nn;
    }
    __syncthreads();
    for (int l = 0; l < 2; ++l) {
        float acc = ldp(wtb, l * 256 + t, f32);
        #pragma unroll
        for (int m = 0; m < 16; ++m)
            acc += ldp(wtW, l * 4096 + t * 16 + m, f32) * mem[l][m];
        hw[l * 256 + t] = acc;
    }
    if (t < 16) {
        post[t]      = ldp(p1W, t, f32) + ldp(p1W, 16 + t, f32);
        post[17 + t] = ldp(paW, t, f32);
    }
    if (t == 0) {
        post[16] = ldp(p1b, 0, f32) + ldp(p1b, 1, f32);
        post[33] = ldp(pab, 0, f32);
    }
}

__global__ void k_convert(const void* __restrict__ p1W, const void* __restrict__ p1b,
                          const void* __restrict__ p2W, const void* __restrict__ p2b,
                          const void* __restrict__ gcnb, const int* __restrict__ flags,
                          float* __restrict__ w1f, float* __restrict__ b1f,
                          float* __restrict__ w2t, float* __restrict__ b2f,
                          float* __restrict__ gcnbf) {
    int f32 = flags[1];
    int i = blockIdx.x * 256 + threadIdx.x;
    if (i < 32768) w1f[i] = ldp(p1W, i, f32);
    if (i < 256)   b1f[i] = ldp(p1b, i, f32);
    if (i < 4096)  { int r = i >> 4, j = i & 15; w2t[i] = ldp(p2W, j * 256 + r, f32); }
    if (i < 16)    b2f[i] = ldp(p2b, i, f32);
    if (i < 32)    gcnbf[i] = ldp(gcnb, i, f32);
}

// ---------------- degree / norm (deg and dinv share one buffer) ----------------
__global__ void k_deg(const int* __restrict__ ei, const int* __restrict__ flags,
                      unsigned* __restrict__ deg, int E, int N) {
    int e = blockIdx.x * 256 + threadIdx.x;
    if (e >= E) return;
    int d = flags[0] ? ei[2 * ((size_t)E + e)] : ei[(size_t)E + e];
    if ((unsigned)d < (unsigned)N) atomicAdd(&deg[d], 1u);
}

__global__ void k_dinv(float* __restrict__ degdinv, int N) {
    int n = blockIdx.x * 256 + threadIdx.x;
    if (n >= N) return;
    unsigned dg = ((unsigned*)degdinv)[n];
    degdinv[n] = 1.f / sqrtf((float)dg + 1.f);  // +1 self loop
}

// ---------------- preprocess: x[128] -> 256 -> 16 -> fp32 h ----------------
__global__ __launch_bounds__(256) void k_pre(const void* __restrict__ x,
                                             const float* __restrict__ w1f,
                                             const float* __restrict__ b1f,
                                             const float* __restrict__ w2t,
                                             const float* __restrict__ b2f,
                                             const int* __restrict__ flags,
                                             float* __restrict__ h, int N) {
    int n = blockIdx.x * 256 + threadIdx.x;
    if (n >= N) return;
    float xr[IN_DIM];
    if (flags[1]) {
        const float4* xp = reinterpret_cast<const float4*>((const float*)x + (size_t)n * IN_DIM);
        #pragma unroll
        for (int i = 0; i < 32; ++i) {
            float4 v = xp[i];
            xr[i * 4 + 0] = v.x; xr[i * 4 + 1] = v.y; xr[i * 4 + 2] = v.z; xr[i * 4 + 3] = v.w;
        }
    } else {
        const uint4* xp = reinterpret_cast<const uint4*>((const unsigned short*)x + (size_t)n * IN_DIM);
        #pragma unroll
        for (int i = 0; i < 16; ++i) unpack8(xp[i], xr + i * 8);
    }
    float acc2[HID];
    #pragma unroll
    for (int j = 0; j < HID; ++j) acc2[j] = b2f[j];
    for (int r = 0; r < PRE_HID; ++r) {
        float s = b1f[r];
        const float* wr = w1f + r * IN_DIM;   // wave-uniform
        #pragma unroll
        for (int k = 0; k < IN_DIM; ++k) s += wr[k] * xr[k];
        s = lrelu(s);
        const float* w2r = w2t + r * HID;
        #pragma unroll
        for (int j = 0; j < HID; ++j) acc2[j] += w2r[j] * s;
    }
    float4* hp = reinterpret_cast<float4*>(h + (size_t)n * HID);
    #pragma unroll
    for (int q = 0; q < 4; ++q) {
        float4 v;
        v.x = lrelu(acc2[q * 4 + 0]); v.y = lrelu(acc2[q * 4 + 1]);
        v.z = lrelu(acc2[q * 4 + 2]); v.w = lrelu(acc2[q * 4 + 3]);
        hp[q] = v;
    }
}

// ---------------- per-layer: xw = h @ W^T ; init acc with self-loop ----------------
__global__ void k_xw(const float* __restrict__ h, const float* __restrict__ W,
                     const float* __restrict__ dinv, const int* __restrict__ flags,
                     void* __restrict__ xw, float* __restrict__ hacc, int N) {
    int n = blockIdx.x * 256 + threadIdx.x;
    if (n >= N) return;
    float hv[HID];
    const float4* hp = reinterpret_cast<const float4*>(h + (size_t)n * HID);
    #pragma unroll
    for (int q = 0; q < 4; ++q) {
        float4 v = hp[q];
        hv[q * 4 + 0] = v.x; hv[q * 4 + 1] = v.y; hv[q * 4 + 2] = v.z; hv[q * 4 + 3] = v.w;
    }
    float dn = dinv[n];
    float sl = dn * dn;
    float o[HID];
    #pragma unroll
    for (int i = 0; i < HID; ++i) {
        float s = 0.f;
        #pragma unroll
        for (int j = 0; j < HID; ++j) s += W[i * HID + j] * hv[j];
        o[i] = s;
    }
    if (flags[1]) {
        float4* xp = reinterpret_cast<float4*>((float*)xw + (size_t)n * HID);
        #pragma unroll
        for (int q = 0; q < 4; ++q) {
            float4 v; v.x = o[q*4+0]; v.y = o[q*4+1]; v.z = o[q*4+2]; v.w = o[q*4+3];
            xp[q] = v;
        }
    } else {
        uint4* xp = reinterpret_cast<uint4*>((unsigned short*)xw + (size_t)n * HID);
        xp[0] = pack8(o);
        xp[1] = pack8(o + 8);
    }
    float4* ap = reinterpret_cast<float4*>(hacc + (size_t)n * HID);
    #pragma unroll
    for (int q = 0; q < 4; ++q) {
        float4 va;
        va.x = o[q*4+0] * sl; va.y = o[q*4+1] * sl; va.z = o[q*4+2] * sl; va.w = o[q*4+3] * sl;
        ap[q] = va;
    }
}

// ---------------- edge scatter ----------------
__global__ __launch_bounds__(256) void k_scatter(const int* __restrict__ ei,
                                                 const int* __restrict__ flags,
                                                 const float* __restrict__ dinv,
                                                 const void* __restrict__ xw,
                                                 float* __restrict__ hacc, int E, int N) {
    int e = blockIdx.x * 256 + threadIdx.x;
    if (e >= E) return;
    int s, d;
    if (flags[0]) { s = ei[2 * (size_t)e]; d = ei[2 * ((size_t)E + e)]; }
    else          { s = ei[e];             d = ei[(size_t)E + e]; }
    if ((unsigned)s >= (unsigned)N || (unsigned)d >= (unsigned)N) return;
    float nrm = dinv[s] * dinv[d];
    float v[HID];
    if (flags[1]) {
        const float4* xr = reinterpret_cast<const float4*>((const float*)xw + (size_t)s * HID);
        #pragma unroll
        for (int q = 0; q < 4; ++q) {
            float4 a = xr[q];
            v[q*4+0] = a.x; v[q*4+1] = a.y; v[q*4+2] = a.z; v[q*4+3] = a.w;
        }
    } else {
        const uint4* xr = reinterpret_cast<const uint4*>((const unsigned short*)xw + (size_t)s * HID);
        unpack8(xr[0], v);
        unpack8(xr[1], v + 8);
    }
    float* out = hacc + (size_t)d * HID;
    #pragma unroll
    for (int j = 0; j < HID; ++j) unsafeAtomicAdd(out + j, v[j] * nrm);
}

// ---------------- finish layer 1: bias + leaky -> fp32 h ----------------
__global__ void k_finish(const float* __restrict__ hacc, const float* __restrict__ gcnbf,
                         float* __restrict__ h, int N) {
    int n = blockIdx.x * 256 + threadIdx.x;
    if (n >= N) return;
    const float4* ap = reinterpret_cast<const float4*>(hacc + (size_t)n * HID);
    float4* hp = reinterpret_cast<float4*>(h + (size_t)n * HID);
    #pragma unroll
    for (int q = 0; q < 4; ++q) {
        float4 a = ap[q];
        float4 o;
        o.x = lrelu(fin(a.x) + gcnbf[q*4+0]);
        o.y = lrelu(fin(a.y) + gcnbf[q*4+1]);
        o.z = lrelu(fin(a.z) + gcnbf[q*4+2]);
        o.w = lrelu(fin(a.w) + gcnbf[q*4+3]);
        hp[q] = o;
    }
}

// ---------------- finish layer 2 + heads, dtype-matched output ----------------
__global__ void k_final(const float* __restrict__ hacc, const float* __restrict__ gcnbf,
                        const float* __restrict__ post, const int* __restrict__ flags,
                        void* __restrict__ out, int N) {
    int n = blockIdx.x * 256 + threadIdx.x;
    if (n >= N) return;
    float v[HID];
    const float4* ap = reinterpret_cast<const float4*>(hacc + (size_t)n * HID);
    #pragma unroll
    for (int q = 0; q < 4; ++q) {
        float4 a = ap[q];
        v[q*4+0] = lrelu(fin(a.x) + gcnbf[q*4+0]);
        v[q*4+1] = lrelu(fin(a.y) + gcnbf[q*4+1]);
        v[q*4+2] = lrelu(fin(a.z) + gcnbf[q*4+2]);
        v[q*4+3] = lrelu(fin(a.w) + gcnbf[q*4+3]);
    }
    float o = post[16], an = post[33];
    #pragma unroll
    for (int j = 0; j < HID; ++j) {
        o += v[j] * post[j];
        an += v[j] * post[17 + j];
    }
    if (flags[1]) {
        float* ob = (float*)out;
        ob[n] = o;
        ob[N + n] = an;
        float* hr = ob + 2 * (size_t)N + (size_t)n * HID;
        #pragma unroll
        for (int j = 0; j < HID; ++j) hr[j] = v[j];
    } else {
        unsigned short* ob = (unsigned short*)out;
        ob[n] = f2bf(o);
        ob[N + n] = f2bf(an);
        uint4* hr = reinterpret_cast<uint4*>(ob + 2 * (size_t)N + (size_t)n * HID);
        hr[0] = pack8(v);
        hr[1] = pack8(v + 8);
    }
}

extern "C" void kernel_launch(void* const* d_in, const int* in_sizes, int n_in,
                              void* d_out, int out_size, void* d_ws, size_t ws_size,
                              hipStream_t stream) {
    const void* x    = d_in[0];
    const int*  ei   = (const int*)d_in[1];
    const void* p1W  = d_in[2];
    const void* p1b  = d_in[3];
    const void* p2W  = d_in[4];
    const void* p2b  = d_in[5];
    const void* bih  = d_in[6];
    const void* bhh  = d_in[7];
    const void* wtW  = d_in[8];
    const void* wtb  = d_in[9];
    const void* gcnb = d_in[10];
    const void* po1W = d_in[11];
    const void* po1b = d_in[12];
    const void* poaW = d_in[13];
    const void* poab = d_in[14];

    const int N = in_sizes[0] / IN_DIM;   // 100000
    const int E = in_sizes[1] / 2;        // 3200000

    // ws requirement: small params + deg/dinv[N] + hacc[16N] + h[16N] (all fp32)
    size_t req_floats = (size_t)OFF_END + (size_t)N + (size_t)N * 16 + (size_t)N * 16;
    if (ws_size < req_floats * 4) {
        // diagnostic sentinel: absmax ~= 256 + ws_MB
        float f = 256.0f + (float)(ws_size >> 20);
        unsigned uv; __builtin_memcpy(&uv, &f, 4);
        int words = out_size / 2;
        k_sentinel<<<(words + 255) / 256, 256, 0, stream>>>((unsigned*)d_out, words, uv);
        return;
    }

    float* ws = (float*)d_ws;
    float* w1f   = ws + OFF_W1F;
    float* b1f   = ws + OFF_B1F;
    float* w2t   = ws + OFF_W2T;
    float* b2f   = ws + OFF_B2F;
    float* hw    = ws + OFF_HW;
    float* gcnbf = ws + OFF_GCNB;
    float* post  = ws + OFF_POST;
    int*   flags = (int*)(ws + OFF_FLAGS);
    float* degdinv = ws + OFF_END;             // uint deg then fp32 dinv in place
    float* hacc  = degdinv + N;                // fp32 [N*16]
    float* h     = hacc + (size_t)N * 16;      // fp32 [N*16]
    void*  xw    = d_out;                      // scratch: bf16 3.2MB or fp32 6.4MB, fits both modes

    const int nb_nodes = (N + 255) / 256;
    const int nb_edges = (E + 255) / 256;

    hipMemsetAsync(degdinv, 0, (size_t)N * 4, stream);
    k_detect<<<1, 64, 0, stream>>>((const unsigned short*)x, ei, flags);
    k_prep_small<<<1, 256, 0, stream>>>(bih, bhh, wtW, wtb, po1W, po1b, poaW, poab,
                                        flags, hw, post);
    k_convert<<<128, 256, 0, stream>>>(p1W, p1b, p2W, p2b, gcnb, flags,
                                       w1f, b1f, w2t, b2f, gcnbf);
    k_deg<<<nb_edges, 256, 0, stream>>>(ei, flags, (unsigned*)degdinv, E, N);
    k_dinv<<<nb_nodes, 256, 0, stream>>>(degdinv, N);
    k_pre<<<nb_nodes, 256, 0, stream>>>(x, w1f, b1f, w2t, b2f, flags, h, N);

    for (int l = 0; l < 2; ++l) {
        k_xw<<<nb_nodes, 256, 0, stream>>>(h, hw + l * 256, degdinv, flags, xw, hacc, N);
        k_scatter<<<nb_edges, 256, 0, stream>>>(ei, flags, degdinv, xw, hacc, E, N);
        if (l == 0) {
            k_finish<<<nb_nodes, 256, 0, stream>>>(hacc, gcnbf + 0, h, N);
        } else {
            k_final<<<nb_nodes, 256, 0, stream>>>(hacc, gcnbf + 16, post, flags, d_out, N);
        }
    }
}

// Round 4
// 1084.667 us; speedup vs baseline: 5.3351x; 5.3351x over previous
//
#include <hip/hip_runtime.h>
#include <hip/hip_bf16.h>
#include <math.h>

#define IN_DIM 128
#define PRE_HID 256
#define HID 16

__device__ __forceinline__ float lrelu(float v) { return v > 0.f ? v : 0.01f * v; }
__device__ __forceinline__ float fin(float v) { return (v == v && fabsf(v) < 1e30f) ? v : 0.f; }

__device__ __forceinline__ float ldp(const void* p, size_t i, int f32) {
    if (f32) return ((const float*)p)[i];
    unsigned u = ((const unsigned short*)p)[i];
    return __uint_as_float(u << 16);
}
__device__ __forceinline__ unsigned short f2bf(float f) {
    union { __hip_bfloat16 b; unsigned short u; } cv;
    cv.b = __float2bfloat16(f);
    return cv.u;
}
__device__ __forceinline__ void unpack8(uint4 u, float* o) {
    o[0] = __uint_as_float(u.x << 16); o[1] = __uint_as_float(u.x & 0xFFFF0000u);
    o[2] = __uint_as_float(u.y << 16); o[3] = __uint_as_float(u.y & 0xFFFF0000u);
    o[4] = __uint_as_float(u.z << 16); o[5] = __uint_as_float(u.z & 0xFFFF0000u);
    o[6] = __uint_as_float(u.w << 16); o[7] = __uint_as_float(u.w & 0xFFFF0000u);
}
__device__ __forceinline__ unsigned pk2(float a, float b) {
    return (unsigned)f2bf(a) | ((unsigned)f2bf(b) << 16);
}
__device__ __forceinline__ uint4 pack8(const float* v) {
    uint4 u;
    u.x = pk2(v[0], v[1]); u.y = pk2(v[2], v[3]);
    u.z = pk2(v[4], v[5]); u.w = pk2(v[6], v[7]);
    return u;
}

// ---- fixed small-param region (float offsets)
#define OFF_W1F   0          // fp32 [32768]
#define OFF_B1F   32768      // fp32 [256]
#define OFF_W2T   33024      // fp32 [4096]
#define OFF_B2F   37120      // fp32 [16]
#define OFF_HW    37136      // fp32 [2][256]
#define OFF_GCNB  37648      // fp32 [2][16]
#define OFF_POST  37680      // fp32 [34] (+pad)
#define OFF_FLAGS 37720      // int [2]: [0]=int64 edges, [1]=fp32 floats
#define OFF_BSUM  37760      // uint [128]
#define OFF_BPRE  37888      // uint [128]
#define OFF_A0    38016      // N-dependent regions start here

// ---------------- dtype detection ----------------
__global__ void k_detect(const unsigned short* __restrict__ xu,
                         const int* __restrict__ ei32, int* __restrict__ flags) {
    if (threadIdx.x == 0 && blockIdx.x == 0) {
        int band = 0;
        for (int k = 0; k < 128; ++k) {
            unsigned e = (xu[2 * k] >> 7) & 0xFF;
            if (e >= 100 && e <= 140) band++;
        }
        flags[1] = (band < 96) ? 1 : 0;  // low in-band => fp32 data
        int any = 0;
        for (int k = 0; k < 64; ++k) any |= ei32[2 * k + 1];
        flags[0] = (any == 0) ? 1 : 0;   // all-zero odd slots => int64
    }
}

__global__ void k_sentinel(unsigned* __restrict__ out, int words, unsigned val) {
    int i = blockIdx.x * 256 + threadIdx.x;
    if (i < words) out[i] = val;
}

// ---------------- small params ----------------
__global__ void k_prep_small(const void* __restrict__ bih, const void* __restrict__ bhh,
                             const void* __restrict__ wtW, const void* __restrict__ wtb,
                             const void* __restrict__ p1W, const void* __restrict__ p1b,
                             const void* __restrict__ paW, const void* __restrict__ pab,
                             const int* __restrict__ flags,
                             float* __restrict__ hw, float* __restrict__ post) {
    int f32 = flags[1];
    __shared__ float mem[2][16];
    int t = threadIdx.x;
    if (t < 32) {
        int l = t >> 4, j = t & 15;
        float bi0 = ldp(bih, l * 48 + j, f32),      bh0 = ldp(bhh, l * 48 + j, f32);
        float bi1 = ldp(bih, l * 48 + 16 + j, f32), bh1 = ldp(bhh, l * 48 + 16 + j, f32);
        float bi2 = ldp(bih, l * 48 + 32 + j, f32), bh2 = ldp(bhh, l * 48 + 32 + j, f32);
        float r = 1.f / (1.f + expf(-(bi0 + bh0)));
        float z = 1.f / (1.f + expf(-(bi1 + bh1)));
        float nn = tanhf(bi2 + r * bh2);
        mem[l][j] = (1.f - z) * nn;
    }
    __syncthreads();
    for (int l = 0; l < 2; ++l) {
        float acc = ldp(wtb, l * 256 + t, f32);
        #pragma unroll
        for (int m = 0; m < 16; ++m)
            acc += ldp(wtW, l * 4096 + t * 16 + m, f32) * mem[l][m];
        hw[l * 256 + t] = acc;
    }
    if (t < 16) {
        post[t]      = ldp(p1W, t, f32) + ldp(p1W, 16 + t, f32);
        post[17 + t] = ldp(paW, t, f32);
    }
    if (t == 0) {
        post[16] = ldp(p1b, 0, f32) + ldp(p1b, 1, f32);
        post[33] = ldp(pab, 0, f32);
    }
}

__global__ void k_convert(const void* __restrict__ p1W, const void* __restrict__ p1b,
                          const void* __restrict__ p2W, const void* __restrict__ p2b,
                          const void* __restrict__ gcnb, const int* __restrict__ flags,
                          float* __restrict__ w1f, float* __restrict__ b1f,
                          float* __restrict__ w2t, float* __restrict__ b2f,
                          float* __restrict__ gcnbf) {
    int f32 = flags[1];
    int i = blockIdx.x * 256 + threadIdx.x;
    if (i < 32768) w1f[i] = ldp(p1W, i, f32);
    if (i < 256)   b1f[i] = ldp(p1b, i, f32);
    if (i < 4096)  { int r = i >> 4, j = i & 15; w2t[i] = ldp(p2W, j * 256 + r, f32); }
    if (i < 16)    b2f[i] = ldp(p2b, i, f32);
    if (i < 32)    gcnbf[i] = ldp(gcnb, i, f32);
}

// ---------------- degree ----------------
__global__ void k_deg(const int* __restrict__ ei, const int* __restrict__ flags,
                      unsigned* __restrict__ deg, int E, int N) {
    int e = blockIdx.x * 256 + threadIdx.x;
    if (e >= E) return;
    int d = flags[0] ? ei[2 * ((size_t)E + e)] : ei[(size_t)E + e];
    if ((unsigned)d < (unsigned)N) atomicAdd(&deg[d], 1u);
}

// in-place deg->dinv (fallback path)
__global__ void k_dinv(float* __restrict__ degdinv, int N) {
    int n = blockIdx.x * 256 + threadIdx.x;
    if (n >= N) return;
    unsigned dg = ((unsigned*)degdinv)[n];
    degdinv[n] = 1.f / sqrtf((float)dg + 1.f);
}

// separate deg->dinv (CSR path)
__global__ void k_dinv2(const unsigned* __restrict__ deg, float* __restrict__ dinv, int N) {
    int n = blockIdx.x * 256 + threadIdx.x;
    if (n >= N) return;
    dinv[n] = 1.f / sqrtf((float)deg[n] + 1.f);
}

// ---------------- prefix scan (3-phase, 1024-wide blocks) ----------------
__global__ __launch_bounds__(1024) void k_scan_block(const unsigned* __restrict__ deg,
                                                     unsigned* __restrict__ bsum, int N) {
    __shared__ unsigned s[1024];
    int t = threadIdx.x;
    int i = blockIdx.x * 1024 + t;
    s[t] = (i < N) ? deg[i] : 0u;
    __syncthreads();
    for (int off = 512; off > 0; off >>= 1) {
        if (t < off) s[t] += s[t + off];
        __syncthreads();
    }
    if (t == 0) bsum[blockIdx.x] = s[0];
}

__global__ __launch_bounds__(128) void k_scan_top(unsigned* __restrict__ bsum,
                                                  unsigned* __restrict__ bpre, int NB) {
    __shared__ unsigned s[128];
    int t = threadIdx.x;
    unsigned v = (t < NB) ? bsum[t] : 0u;
    s[t] = v;
    __syncthreads();
    for (int off = 1; off < 128; off <<= 1) {
        unsigned a = (t >= off) ? s[t - off] : 0u;
        __syncthreads();
        s[t] += a;
        __syncthreads();
    }
    if (t < NB) bpre[t] = s[t] - v;  // exclusive
}

__global__ __launch_bounds__(1024) void k_scan_final(const unsigned* __restrict__ deg,
                                                     const unsigned* __restrict__ bpre,
                                                     unsigned* __restrict__ rowptr, int N) {
    __shared__ unsigned s[1024];
    int t = threadIdx.x;
    int i = blockIdx.x * 1024 + t;
    unsigned v = (i < N) ? deg[i] : 0u;
    s[t] = v;
    __syncthreads();
    for (int off = 1; off < 1024; off <<= 1) {
        unsigned a = (t >= off) ? s[t - off] : 0u;
        __syncthreads();
        s[t] += a;
        __syncthreads();
    }
    if (i < N) rowptr[i] = bpre[blockIdx.x] + s[t] - v;  // exclusive prefix
}

// ---------------- CSR fill (counting sort) ----------------
__global__ void k_fill(const int* __restrict__ ei, const int* __restrict__ flags,
                       unsigned* __restrict__ rowptr, unsigned* __restrict__ csr,
                       int E, int N) {
    int e = blockIdx.x * 256 + threadIdx.x;
    if (e >= E) return;
    int s, d;
    if (flags[0]) { s = ei[2 * (size_t)e]; d = ei[2 * ((size_t)E + e)]; }
    else          { s = ei[e];             d = ei[(size_t)E + e]; }
    if ((unsigned)d >= (unsigned)N) return;
    if ((unsigned)s >= (unsigned)N) s = d;  // keep slot defined (shouldn't happen)
    unsigned pos = atomicAdd(&rowptr[d], 1u);
    csr[pos] = (unsigned)s;
}

// ---------------- preprocess: x[128] -> 256 -> 16 -> fp32 h ----------------
__global__ __launch_bounds__(256) void k_pre(const void* __restrict__ x,
                                             const float* __restrict__ w1f,
                                             const float* __restrict__ b1f,
                                             const float* __restrict__ w2t,
                                             const float* __restrict__ b2f,
                                             const int* __restrict__ flags,
                                             float* __restrict__ h, int N) {
    int n = blockIdx.x * 256 + threadIdx.x;
    if (n >= N) return;
    float xr[IN_DIM];
    if (flags[1]) {
        const float4* xp = reinterpret_cast<const float4*>((const float*)x + (size_t)n * IN_DIM);
        #pragma unroll
        for (int i = 0; i < 32; ++i) {
            float4 v = xp[i];
            xr[i * 4 + 0] = v.x; xr[i * 4 + 1] = v.y; xr[i * 4 + 2] = v.z; xr[i * 4 + 3] = v.w;
        }
    } else {
        const uint4* xp = reinterpret_cast<const uint4*>((const unsigned short*)x + (size_t)n * IN_DIM);
        #pragma unroll
        for (int i = 0; i < 16; ++i) unpack8(xp[i], xr + i * 8);
    }
    float acc2[HID];
    #pragma unroll
    for (int j = 0; j < HID; ++j) acc2[j] = b2f[j];
    for (int r = 0; r < PRE_HID; ++r) {
        float s = b1f[r];
        const float* wr = w1f + r * IN_DIM;   // wave-uniform
        #pragma unroll
        for (int k = 0; k < IN_DIM; ++k) s += wr[k] * xr[k];
        s = lrelu(s);
        const float* w2r = w2t + r * HID;
        #pragma unroll
        for (int j = 0; j < HID; ++j) acc2[j] += w2r[j] * s;
    }
    float4* hp = reinterpret_cast<float4*>(h + (size_t)n * HID);
    #pragma unroll
    for (int q = 0; q < 4; ++q) {
        float4 v;
        v.x = lrelu(acc2[q * 4 + 0]); v.y = lrelu(acc2[q * 4 + 1]);
        v.z = lrelu(acc2[q * 4 + 2]); v.w = lrelu(acc2[q * 4 + 3]);
        hp[q] = v;
    }
}

// ---------------- CSR path: y = (h @ W^T) * dinv[n] ----------------
__global__ void k_xw_y(const float* __restrict__ h, const float* __restrict__ W,
                       const float* __restrict__ dinv, float* __restrict__ y, int N) {
    int n = blockIdx.x * 256 + threadIdx.x;
    if (n >= N) return;
    float hv[HID];
    const float4* hp = reinterpret_cast<const float4*>(h + (size_t)n * HID);
    #pragma unroll
    for (int q = 0; q < 4; ++q) {
        float4 v = hp[q];
        hv[q*4+0] = v.x; hv[q*4+1] = v.y; hv[q*4+2] = v.z; hv[q*4+3] = v.w;
    }
    float dn = dinv[n];
    float4* yp = reinterpret_cast<float4*>(y + (size_t)n * HID);
    #pragma unroll
    for (int q = 0; q < 4; ++q) {
        float o[4];
        #pragma unroll
        for (int ii = 0; ii < 4; ++ii) {
            int i = q * 4 + ii;
            float s = 0.f;
            #pragma unroll
            for (int j = 0; j < HID; ++j) s += W[i * HID + j] * hv[j];
            o[ii] = s * dn;
        }
        float4 v; v.x = o[0]; v.y = o[1]; v.z = o[2]; v.w = o[3];
        yp[q] = v;
    }
}

// ---------------- CSR gather: h = lrelu(dinv[n]*(y[n] + sum y[src]) + b) ----------------
__global__ __launch_bounds__(256) void k_gather(const unsigned* __restrict__ rowptr,
                                                const unsigned* __restrict__ deg,
                                                const unsigned* __restrict__ csr,
                                                const float* __restrict__ y,
                                                const float* __restrict__ dinv,
                                                const float* __restrict__ gcnbf,
                                                float* __restrict__ h, int N) {
    int tid = blockIdx.x * 256 + threadIdx.x;
    if (tid >= N * HID) return;
    int n = tid >> 4, f = tid & 15;
    unsigned end = rowptr[n];           // post-fill: inclusive end
    unsigned start = end - deg[n];
    float acc = y[(size_t)n * HID + f]; // self-loop term (dinv[n] folded in y)
    for (unsigned k = start; k < end; ++k) {
        unsigned src = csr[k];
        acc += y[(size_t)src * HID + f];
    }
    h[(size_t)n * HID + f] = lrelu(fin(dinv[n] * acc) + gcnbf[f]);
}

// ---------------- CSR gather, final layer: + heads, dtype-matched output ----------------
__global__ __launch_bounds__(256) void k_gather_final(const unsigned* __restrict__ rowptr,
                                                      const unsigned* __restrict__ deg,
                                                      const unsigned* __restrict__ csr,
                                                      const float* __restrict__ y,
                                                      const float* __restrict__ dinv,
                                                      const float* __restrict__ gcnbf,
                                                      const float* __restrict__ post,
                                                      const int* __restrict__ flags,
                                                      void* __restrict__ out, int N) {
    int tid = blockIdx.x * 256 + threadIdx.x;
    if (tid >= N * HID) return;
    int n = tid >> 4, f = tid & 15;
    unsigned end = rowptr[n];
    unsigned start = end - deg[n];
    float acc = y[(size_t)n * HID + f];
    for (unsigned k = start; k < end; ++k) {
        unsigned src = csr[k];
        acc += y[(size_t)src * HID + f];
    }
    float v = lrelu(fin(dinv[n] * acc) + gcnbf[f]);
    float s1 = v * post[f];
    float s2 = v * post[17 + f];
    #pragma unroll
    for (int m = 1; m < 16; m <<= 1) {
        s1 += __shfl_xor(s1, m, 64);
        s2 += __shfl_xor(s2, m, 64);
    }
    if (flags[1]) {
        float* ob = (float*)out;
        if (f == 0) ob[n] = s1 + post[16];
        if (f == 1) ob[N + n] = s2 + post[33];
        ob[2 * (size_t)N + (size_t)n * HID + f] = v;
    } else {
        unsigned short* ob = (unsigned short*)out;
        if (f == 0) ob[n] = f2bf(s1 + post[16]);
        if (f == 1) ob[N + n] = f2bf(s2 + post[33]);
        ob[2 * (size_t)N + (size_t)n * HID + f] = f2bf(v);
    }
}

// ================= fallback (atomic) path kernels =================
__global__ void k_xw(const float* __restrict__ h, const float* __restrict__ W,
                     const float* __restrict__ dinv, const int* __restrict__ flags,
                     void* __restrict__ xw, float* __restrict__ hacc, int N) {
    int n = blockIdx.x * 256 + threadIdx.x;
    if (n >= N) return;
    float hv[HID];
    const float4* hp = reinterpret_cast<const float4*>(h + (size_t)n * HID);
    #pragma unroll
    for (int q = 0; q < 4; ++q) {
        float4 v = hp[q];
        hv[q*4+0] = v.x; hv[q*4+1] = v.y; hv[q*4+2] = v.z; hv[q*4+3] = v.w;
    }
    float dn = dinv[n];
    float sl = dn * dn;
    float o[HID];
    #pragma unroll
    for (int i = 0; i < HID; ++i) {
        float s = 0.f;
        #pragma unroll
        for (int j = 0; j < HID; ++j) s += W[i * HID + j] * hv[j];
        o[i] = s;
    }
    if (flags[1]) {
        float4* xp = reinterpret_cast<float4*>((float*)xw + (size_t)n * HID);
        #pragma unroll
        for (int q = 0; q < 4; ++q) {
            float4 v; v.x = o[q*4+0]; v.y = o[q*4+1]; v.z = o[q*4+2]; v.w = o[q*4+3];
            xp[q] = v;
        }
    } else {
        uint4* xp = reinterpret_cast<uint4*>((unsigned short*)xw + (size_t)n * HID);
        xp[0] = pack8(o);
        xp[1] = pack8(o + 8);
    }
    float4* ap = reinterpret_cast<float4*>(hacc + (size_t)n * HID);
    #pragma unroll
    for (int q = 0; q < 4; ++q) {
        float4 va;
        va.x = o[q*4+0]*sl; va.y = o[q*4+1]*sl; va.z = o[q*4+2]*sl; va.w = o[q*4+3]*sl;
        ap[q] = va;
    }
}

__global__ __launch_bounds__(256) void k_scatter(const int* __restrict__ ei,
                                                 const int* __restrict__ flags,
                                                 const float* __restrict__ dinv,
                                                 const void* __restrict__ xw,
                                                 float* __restrict__ hacc, int E, int N) {
    int e = blockIdx.x * 256 + threadIdx.x;
    if (e >= E) return;
    int s, d;
    if (flags[0]) { s = ei[2 * (size_t)e]; d = ei[2 * ((size_t)E + e)]; }
    else          { s = ei[e];             d = ei[(size_t)E + e]; }
    if ((unsigned)s >= (unsigned)N || (unsigned)d >= (unsigned)N) return;
    float nrm = dinv[s] * dinv[d];
    float v[HID];
    if (flags[1]) {
        const float4* xr = reinterpret_cast<const float4*>((const float*)xw + (size_t)s * HID);
        #pragma unroll
        for (int q = 0; q < 4; ++q) {
            float4 a = xr[q];
            v[q*4+0] = a.x; v[q*4+1] = a.y; v[q*4+2] = a.z; v[q*4+3] = a.w;
        }
    } else {
        const uint4* xr = reinterpret_cast<const uint4*>((const unsigned short*)xw + (size_t)s * HID);
        unpack8(xr[0], v);
        unpack8(xr[1], v + 8);
    }
    float* out = hacc + (size_t)d * HID;
    #pragma unroll
    for (int j = 0; j < HID; ++j) unsafeAtomicAdd(out + j, v[j] * nrm);
}

__global__ void k_finish(const float* __restrict__ hacc, const float* __restrict__ gcnbf,
                         float* __restrict__ h, int N) {
    int n = blockIdx.x * 256 + threadIdx.x;
    if (n >= N) return;
    const float4* ap = reinterpret_cast<const float4*>(hacc + (size_t)n * HID);
    float4* hp = reinterpret_cast<float4*>(h + (size_t)n * HID);
    #pragma unroll
    for (int q = 0; q < 4; ++q) {
        float4 a = ap[q];
        float4 o;
        o.x = lrelu(fin(a.x) + gcnbf[q*4+0]);
        o.y = lrelu(fin(a.y) + gcnbf[q*4+1]);
        o.z = lrelu(fin(a.z) + gcnbf[q*4+2]);
        o.w = lrelu(fin(a.w) + gcnbf[q*4+3]);
        hp[q] = o;
    }
}

__global__ void k_final(const float* __restrict__ hacc, const float* __restrict__ gcnbf,
                        const float* __restrict__ post, const int* __restrict__ flags,
                        void* __restrict__ out, int N) {
    int n = blockIdx.x * 256 + threadIdx.x;
    if (n >= N) return;
    float v[HID];
    const float4* ap = reinterpret_cast<const float4*>(hacc + (size_t)n * HID);
    #pragma unroll
    for (int q = 0; q < 4; ++q) {
        float4 a = ap[q];
        v[q*4+0] = lrelu(fin(a.x) + gcnbf[q*4+0]);
        v[q*4+1] = lrelu(fin(a.y) + gcnbf[q*4+1]);
        v[q*4+2] = lrelu(fin(a.z) + gcnbf[q*4+2]);
        v[q*4+3] = lrelu(fin(a.w) + gcnbf[q*4+3]);
    }
    float o = post[16], an = post[33];
    #pragma unroll
    for (int j = 0; j < HID; ++j) {
        o += v[j] * post[j];
        an += v[j] * post[17 + j];
    }
    if (flags[1]) {
        float* ob = (float*)out;
        ob[n] = o;
        ob[N + n] = an;
        float* hr = ob + 2 * (size_t)N + (size_t)n * HID;
        #pragma unroll
        for (int j = 0; j < HID; ++j) hr[j] = v[j];
    } else {
        unsigned short* ob = (unsigned short*)out;
        ob[n] = f2bf(o);
        ob[N + n] = f2bf(an);
        uint4* hr = reinterpret_cast<uint4*>(ob + 2 * (size_t)N + (size_t)n * HID);
        hr[0] = pack8(v);
        hr[1] = pack8(v + 8);
    }
}

extern "C" void kernel_launch(void* const* d_in, const int* in_sizes, int n_in,
                              void* d_out, int out_size, void* d_ws, size_t ws_size,
                              hipStream_t stream) {
    const void* x    = d_in[0];
    const int*  ei   = (const int*)d_in[1];
    const void* p1W  = d_in[2];
    const void* p1b  = d_in[3];
    const void* p2W  = d_in[4];
    const void* p2b  = d_in[5];
    const void* bih  = d_in[6];
    const void* bhh  = d_in[7];
    const void* wtW  = d_in[8];
    const void* wtb  = d_in[9];
    const void* gcnb = d_in[10];
    const void* po1W = d_in[11];
    const void* po1b = d_in[12];
    const void* poaW = d_in[13];
    const void* poab = d_in[14];

    const int N = in_sizes[0] / IN_DIM;   // 100000
    const int E = in_sizes[1] / 2;        // 3200000

    float* ws = (float*)d_ws;
    float* w1f   = ws + OFF_W1F;
    float* b1f   = ws + OFF_B1F;
    float* w2t   = ws + OFF_W2T;
    float* b2f   = ws + OFF_B2F;
    float* hw    = ws + OFF_HW;
    float* gcnbf = ws + OFF_GCNB;
    float* post  = ws + OFF_POST;
    int*   flags = (int*)(ws + OFF_FLAGS);
    unsigned* bsum = (unsigned*)(ws + OFF_BSUM);
    unsigned* bpre = (unsigned*)(ws + OFF_BPRE);

    const int nb_nodes = (N + 255) / 256;
    const int nb_edges = (E + 255) / 256;
    const int nb_nf    = (N * HID + 255) / 256;
    const int NB       = (N + 1023) / 1024;

    // CSR path requirement: deg[N] + rowptr[N] + dinv[N] + csr[E] + y[16N] + h[16N]
    size_t req_csr = ((size_t)OFF_A0 + 35 * (size_t)N + (size_t)E + 64) * 4;
    size_t req_fb  = ((size_t)OFF_A0 + 33 * (size_t)N + 64) * 4;

    if (ws_size >= req_csr && NB <= 128) {
        // ================= CSR (pull) path =================
        unsigned* deg    = (unsigned*)(ws + OFF_A0);
        unsigned* rowptr = deg + N;
        float*    dinv   = (float*)(rowptr + N);
        unsigned* csr    = (unsigned*)(dinv + N);
        float*    y      = (float*)(csr + E);
        float*    h      = y + (size_t)N * HID;

        hipMemsetAsync(deg, 0, (size_t)N * 4, stream);
        k_detect<<<1, 64, 0, stream>>>((const unsigned short*)x, ei, flags);
        k_prep_small<<<1, 256, 0, stream>>>(bih, bhh, wtW, wtb, po1W, po1b, poaW, poab,
                                            flags, hw, post);
        k_convert<<<128, 256, 0, stream>>>(p1W, p1b, p2W, p2b, gcnb, flags,
                                           w1f, b1f, w2t, b2f, gcnbf);
        k_deg<<<nb_edges, 256, 0, stream>>>(ei, flags, deg, E, N);
        k_dinv2<<<nb_nodes, 256, 0, stream>>>(deg, dinv, N);
        k_scan_block<<<NB, 1024, 0, stream>>>(deg, bsum, N);
        k_scan_top<<<1, 128, 0, stream>>>(bsum, bpre, NB);
        k_scan_final<<<NB, 1024, 0, stream>>>(deg, bpre, rowptr, N);
        k_fill<<<nb_edges, 256, 0, stream>>>(ei, flags, rowptr, csr, E, N);
        k_pre<<<nb_nodes, 256, 0, stream>>>(x, w1f, b1f, w2t, b2f, flags, h, N);

        k_xw_y<<<nb_nodes, 256, 0, stream>>>(h, hw + 0, dinv, y, N);
        k_gather<<<nb_nf, 256, 0, stream>>>(rowptr, deg, csr, y, dinv, gcnbf + 0, h, N);
        k_xw_y<<<nb_nodes, 256, 0, stream>>>(h, hw + 256, dinv, y, N);
        k_gather_final<<<nb_nf, 256, 0, stream>>>(rowptr, deg, csr, y, dinv, gcnbf + 16,
                                                  post, flags, d_out, N);
    } else if (ws_size >= req_fb) {
        // ================= fallback (atomic) path =================
        float* degdinv = ws + OFF_A0;
        float* hacc    = degdinv + N;
        float* h       = hacc + (size_t)N * HID;
        void*  xw      = d_out;

        hipMemsetAsync(degdinv, 0, (size_t)N * 4, stream);
        k_detect<<<1, 64, 0, stream>>>((const unsigned short*)x, ei, flags);
        k_prep_small<<<1, 256, 0, stream>>>(bih, bhh, wtW, wtb, po1W, po1b, poaW, poab,
                                            flags, hw, post);
        k_convert<<<128, 256, 0, stream>>>(p1W, p1b, p2W, p2b, gcnb, flags,
                                           w1f, b1f, w2t, b2f, gcnbf);
        k_deg<<<nb_edges, 256, 0, stream>>>(ei, flags, (unsigned*)degdinv, E, N);
        k_dinv<<<nb_nodes, 256, 0, stream>>>(degdinv, N);
        k_pre<<<nb_nodes, 256, 0, stream>>>(x, w1f, b1f, w2t, b2f, flags, h, N);
        for (int l = 0; l < 2; ++l) {
            k_xw<<<nb_nodes, 256, 0, stream>>>(h, hw + l * 256, degdinv, flags, xw, hacc, N);
            k_scatter<<<nb_edges, 256, 0, stream>>>(ei, flags, degdinv, xw, hacc, E, N);
            if (l == 0) k_finish<<<nb_nodes, 256, 0, stream>>>(hacc, gcnbf + 0, h, N);
            else        k_final<<<nb_nodes, 256, 0, stream>>>(hacc, gcnbf + 16, post, flags, d_out, N);
        }
    } else {
        float f = 256.0f + (float)(ws_size >> 20);
        unsigned uv; __builtin_memcpy(&uv, &f, 4);
        int words = out_size / 2;
        k_sentinel<<<(words + 255) / 256, 256, 0, stream>>>((unsigned*)d_out, words, uv);
    }
}

// Round 5
// 979.442 us; speedup vs baseline: 5.9083x; 1.1074x over previous
//
#include <hip/hip_runtime.h>
#include <hip/hip_bf16.h>
#include <math.h>

#define IN_DIM 128
#define PRE_HID 256
#define HID 16

__device__ __forceinline__ float lrelu(float v) { return v > 0.f ? v : 0.01f * v; }
__device__ __forceinline__ float fin(float v) { return (v == v && fabsf(v) < 1e30f) ? v : 0.f; }

__device__ __forceinline__ float ldp(const void* p, size_t i, int f32) {
    if (f32) return ((const float*)p)[i];
    unsigned u = ((const unsigned short*)p)[i];
    return __uint_as_float(u << 16);
}
__device__ __forceinline__ unsigned short f2bf(float f) {
    union { __hip_bfloat16 b; unsigned short u; } cv;
    cv.b = __float2bfloat16(f);
    return cv.u;
}
__device__ __forceinline__ void unpack8(uint4 u, float* o) {
    o[0] = __uint_as_float(u.x << 16); o[1] = __uint_as_float(u.x & 0xFFFF0000u);
    o[2] = __uint_as_float(u.y << 16); o[3] = __uint_as_float(u.y & 0xFFFF0000u);
    o[4] = __uint_as_float(u.z << 16); o[5] = __uint_as_float(u.z & 0xFFFF0000u);
    o[6] = __uint_as_float(u.w << 16); o[7] = __uint_as_float(u.w & 0xFFFF0000u);
}
__device__ __forceinline__ unsigned pk2(float a, float b) {
    return (unsigned)f2bf(a) | ((unsigned)f2bf(b) << 16);
}
__device__ __forceinline__ uint4 pack8(const float* v) {
    uint4 u;
    u.x = pk2(v[0], v[1]); u.y = pk2(v[2], v[3]);
    u.z = pk2(v[4], v[5]); u.w = pk2(v[6], v[7]);
    return u;
}

// ---- fixed small-param region (float offsets)
#define OFF_W1F   0          // fp32 [32768]
#define OFF_B1F   32768      // fp32 [256]
#define OFF_W2T   33024      // fp32 [4096]
#define OFF_B2F   37120      // fp32 [16]
#define OFF_HW    37136      // fp32 [2][256]
#define OFF_GCNB  37648      // fp32 [2][16]
#define OFF_POST  37680      // fp32 [34] (+pad)
#define OFF_FLAGS 37720      // int [2]: [0]=int64 edges, [1]=fp32 floats
#define OFF_BSUM  37760      // uint [128]
#define OFF_BPRE  37888      // uint [128]
#define OFF_A0    38016      // N-dependent regions start here

// ---------------- dtype detection ----------------
__global__ void k_detect(const unsigned short* __restrict__ xu,
                         const int* __restrict__ ei32, int* __restrict__ flags) {
    if (threadIdx.x == 0 && blockIdx.x == 0) {
        int band = 0;
        for (int k = 0; k < 128; ++k) {
            unsigned e = (xu[2 * k] >> 7) & 0xFF;
            if (e >= 100 && e <= 140) band++;
        }
        flags[1] = (band < 96) ? 1 : 0;  // low in-band => fp32 data
        int any = 0;
        for (int k = 0; k < 64; ++k) any |= ei32[2 * k + 1];
        flags[0] = (any == 0) ? 1 : 0;   // all-zero odd slots => int64
    }
}

__global__ void k_sentinel(unsigned* __restrict__ out, int words, unsigned val) {
    int i = blockIdx.x * 256 + threadIdx.x;
    if (i < words) out[i] = val;
}

// ---------------- small params ----------------
__global__ void k_prep_small(const void* __restrict__ bih, const void* __restrict__ bhh,
                             const void* __restrict__ wtW, const void* __restrict__ wtb,
                             const void* __restrict__ p1W, const void* __restrict__ p1b,
                             const void* __restrict__ paW, const void* __restrict__ pab,
                             const int* __restrict__ flags,
                             float* __restrict__ hw, float* __restrict__ post) {
    int f32 = flags[1];
    __shared__ float mem[2][16];
    int t = threadIdx.x;
    if (t < 32) {
        int l = t >> 4, j = t & 15;
        float bi0 = ldp(bih, l * 48 + j, f32),      bh0 = ldp(bhh, l * 48 + j, f32);
        float bi1 = ldp(bih, l * 48 + 16 + j, f32), bh1 = ldp(bhh, l * 48 + 16 + j, f32);
        float bi2 = ldp(bih, l * 48 + 32 + j, f32), bh2 = ldp(bhh, l * 48 + 32 + j, f32);
        float r = 1.f / (1.f + expf(-(bi0 + bh0)));
        float z = 1.f / (1.f + expf(-(bi1 + bh1)));
        float nn = tanhf(bi2 + r * bh2);
        mem[l][j] = (1.f - z) * nn;
    }
    __syncthreads();
    for (int l = 0; l < 2; ++l) {
        float acc = ldp(wtb, l * 256 + t, f32);
        #pragma unroll
        for (int m = 0; m < 16; ++m)
            acc += ldp(wtW, l * 4096 + t * 16 + m, f32) * mem[l][m];
        hw[l * 256 + t] = acc;
    }
    if (t < 16) {
        post[t]      = ldp(p1W, t, f32) + ldp(p1W, 16 + t, f32);
        post[17 + t] = ldp(paW, t, f32);
    }
    if (t == 0) {
        post[16] = ldp(p1b, 0, f32) + ldp(p1b, 1, f32);
        post[33] = ldp(pab, 0, f32);
    }
}

__global__ void k_convert(const void* __restrict__ p1W, const void* __restrict__ p1b,
                          const void* __restrict__ p2W, const void* __restrict__ p2b,
                          const void* __restrict__ gcnb, const int* __restrict__ flags,
                          float* __restrict__ w1f, float* __restrict__ b1f,
                          float* __restrict__ w2t, float* __restrict__ b2f,
                          float* __restrict__ gcnbf) {
    int f32 = flags[1];
    int i = blockIdx.x * 256 + threadIdx.x;
    if (i < 32768) w1f[i] = ldp(p1W, i, f32);
    if (i < 256)   b1f[i] = ldp(p1b, i, f32);
    if (i < 4096)  { int r = i >> 4, j = i & 15; w2t[i] = ldp(p2W, j * 256 + r, f32); }
    if (i < 16)    b2f[i] = ldp(p2b, i, f32);
    if (i < 32)    gcnbf[i] = ldp(gcnb, i, f32);
}

// ---------------- degree ----------------
__global__ void k_deg(const int* __restrict__ ei, const int* __restrict__ flags,
                      unsigned* __restrict__ deg, int E, int N) {
    int e = blockIdx.x * 256 + threadIdx.x;
    if (e >= E) return;
    int d = flags[0] ? ei[2 * ((size_t)E + e)] : ei[(size_t)E + e];
    if ((unsigned)d < (unsigned)N) atomicAdd(&deg[d], 1u);
}

__global__ void k_dinv(float* __restrict__ degdinv, int N) {
    int n = blockIdx.x * 256 + threadIdx.x;
    if (n >= N) return;
    unsigned dg = ((unsigned*)degdinv)[n];
    degdinv[n] = 1.f / sqrtf((float)dg + 1.f);
}

__global__ void k_dinv2(const unsigned* __restrict__ deg, float* __restrict__ dinv, int N) {
    int n = blockIdx.x * 256 + threadIdx.x;
    if (n >= N) return;
    dinv[n] = 1.f / sqrtf((float)deg[n] + 1.f);
}

// ---------------- prefix scan ----------------
__global__ __launch_bounds__(1024) void k_scan_block(const unsigned* __restrict__ deg,
                                                     unsigned* __restrict__ bsum, int N) {
    __shared__ unsigned s[1024];
    int t = threadIdx.x;
    int i = blockIdx.x * 1024 + t;
    s[t] = (i < N) ? deg[i] : 0u;
    __syncthreads();
    for (int off = 512; off > 0; off >>= 1) {
        if (t < off) s[t] += s[t + off];
        __syncthreads();
    }
    if (t == 0) bsum[blockIdx.x] = s[0];
}

__global__ __launch_bounds__(128) void k_scan_top(unsigned* __restrict__ bsum,
                                                  unsigned* __restrict__ bpre, int NB) {
    __shared__ unsigned s[128];
    int t = threadIdx.x;
    unsigned v = (t < NB) ? bsum[t] : 0u;
    s[t] = v;
    __syncthreads();
    for (int off = 1; off < 128; off <<= 1) {
        unsigned a = (t >= off) ? s[t - off] : 0u;
        __syncthreads();
        s[t] += a;
        __syncthreads();
    }
    if (t < NB) bpre[t] = s[t] - v;
}

__global__ __launch_bounds__(1024) void k_scan_final(const unsigned* __restrict__ deg,
                                                     const unsigned* __restrict__ bpre,
                                                     unsigned* __restrict__ rowptr, int N) {
    __shared__ unsigned s[1024];
    int t = threadIdx.x;
    int i = blockIdx.x * 1024 + t;
    unsigned v = (i < N) ? deg[i] : 0u;
    s[t] = v;
    __syncthreads();
    for (int off = 1; off < 1024; off <<= 1) {
        unsigned a = (t >= off) ? s[t - off] : 0u;
        __syncthreads();
        s[t] += a;
        __syncthreads();
    }
    if (i < N) rowptr[i] = bpre[blockIdx.x] + s[t] - v;
}

// ---------------- CSR fill ----------------
__global__ void k_fill(const int* __restrict__ ei, const int* __restrict__ flags,
                       unsigned* __restrict__ rowptr, unsigned* __restrict__ csr,
                       int E, int N) {
    int e = blockIdx.x * 256 + threadIdx.x;
    if (e >= E) return;
    int s, d;
    if (flags[0]) { s = ei[2 * (size_t)e]; d = ei[2 * ((size_t)E + e)]; }
    else          { s = ei[e];             d = ei[(size_t)E + e]; }
    if ((unsigned)d >= (unsigned)N) return;
    if ((unsigned)s >= (unsigned)N) s = d;
    unsigned pos = atomicAdd(&rowptr[d], 1u);
    csr[pos] = (unsigned)s;
}

// ---------------- preprocess: register-blocked GEMM, no spill ----------------
// x[n,128] -> lrelu(@W1^T+b1)[256] -> lrelu(@W2^T+b2)[16]
// 8 tiles of 32 rows; s[32] accumulators in VGPRs; W via wave-uniform s_loads.
__global__ __launch_bounds__(256) void k_pre(const void* __restrict__ x,
                                             const float* __restrict__ w1f,
                                             const float* __restrict__ b1f,
                                             const float* __restrict__ w2t,
                                             const float* __restrict__ b2f,
                                             const int* __restrict__ flags,
                                             float* __restrict__ h, int N) {
    int n = blockIdx.x * 256 + threadIdx.x;
    if (n >= N) return;
    const int f32 = flags[1];
    const float* xf = (const float*)x + (size_t)n * IN_DIM;
    const unsigned short* xb = (const unsigned short*)x + (size_t)n * IN_DIM;

    float acc2[HID];
    #pragma unroll
    for (int j = 0; j < HID; ++j) acc2[j] = b2f[j];

    for (int rt = 0; rt < 8; ++rt) {          // 32-row tiles of layer-1
        float s[32];
        #pragma unroll
        for (int r = 0; r < 32; ++r) s[r] = b1f[rt * 32 + r];
        for (int kc = 0; kc < 16; ++kc) {     // 8-wide k chunks
            float xr[8];
            if (f32) {
                float4 a = *reinterpret_cast<const float4*>(xf + kc * 8);
                float4 b = *reinterpret_cast<const float4*>(xf + kc * 8 + 4);
                xr[0] = a.x; xr[1] = a.y; xr[2] = a.z; xr[3] = a.w;
                xr[4] = b.x; xr[5] = b.y; xr[6] = b.z; xr[7] = b.w;
            } else {
                uint4 u = *reinterpret_cast<const uint4*>(xb + kc * 8);
                unpack8(u, xr);
            }
            const float* wbase = w1f + (size_t)(rt * 32) * IN_DIM + kc * 8;
            #pragma unroll
            for (int r = 0; r < 32; ++r) {
                const float* wr = wbase + (size_t)r * IN_DIM;  // wave-uniform
                #pragma unroll
                for (int k = 0; k < 8; ++k) s[r] += wr[k] * xr[k];
            }
        }
        const float* w2base = w2t + (size_t)(rt * 32) * HID;
        #pragma unroll
        for (int r = 0; r < 32; ++r) {
            float t = lrelu(s[r]);
            const float* w2r = w2base + (size_t)r * HID;       // wave-uniform
            #pragma unroll
            for (int j = 0; j < HID; ++j) acc2[j] += w2r[j] * t;
        }
    }
    float4* hp = reinterpret_cast<float4*>(h + (size_t)n * HID);
    #pragma unroll
    for (int q = 0; q < 4; ++q) {
        float4 v;
        v.x = lrelu(acc2[q * 4 + 0]); v.y = lrelu(acc2[q * 4 + 1]);
        v.z = lrelu(acc2[q * 4 + 2]); v.w = lrelu(acc2[q * 4 + 3]);
        hp[q] = v;
    }
}

// ---------------- CSR path: y = (h @ W^T) * dinv[n] ----------------
__global__ void k_xw_y(const float* __restrict__ h, const float* __restrict__ W,
                       const float* __restrict__ dinv, float* __restrict__ y, int N) {
    int n = blockIdx.x * 256 + threadIdx.x;
    if (n >= N) return;
    float hv[HID];
    const float4* hp = reinterpret_cast<const float4*>(h + (size_t)n * HID);
    #pragma unroll
    for (int q = 0; q < 4; ++q) {
        float4 v = hp[q];
        hv[q*4+0] = v.x; hv[q*4+1] = v.y; hv[q*4+2] = v.z; hv[q*4+3] = v.w;
    }
    float dn = dinv[n];
    float4* yp = reinterpret_cast<float4*>(y + (size_t)n * HID);
    #pragma unroll
    for (int q = 0; q < 4; ++q) {
        float o[4];
        #pragma unroll
        for (int ii = 0; ii < 4; ++ii) {
            int i = q * 4 + ii;
            float s = 0.f;
            #pragma unroll
            for (int j = 0; j < HID; ++j) s += W[i * HID + j] * hv[j];
            o[ii] = s * dn;
        }
        float4 v; v.x = o[0]; v.y = o[1]; v.z = o[2]; v.w = o[3];
        yp[q] = v;
    }
}

// ---------------- CSR gather: 4 lanes per node, float4 per lane ----------------
__global__ __launch_bounds__(256) void k_gather(const unsigned* __restrict__ rowptr,
                                                const unsigned* __restrict__ deg,
                                                const unsigned* __restrict__ csr,
                                                const float* __restrict__ y,
                                                const float* __restrict__ dinv,
                                                const float* __restrict__ gcnbf,
                                                float* __restrict__ h, int N) {
    int tid = blockIdx.x * 256 + threadIdx.x;
    if (tid >= N * 4) return;
    int n = tid >> 2, q = tid & 3;
    unsigned end = rowptr[n];
    unsigned start = end - deg[n];
    float4 acc = *reinterpret_cast<const float4*>(y + (size_t)n * HID + q * 4);
    for (unsigned k = start; k < end; ++k) {
        unsigned src = csr[k];
        float4 v = *reinterpret_cast<const float4*>(y + (size_t)src * HID + q * 4);
        acc.x += v.x; acc.y += v.y; acc.z += v.z; acc.w += v.w;
    }
    float dn = dinv[n];
    float4 o;
    o.x = lrelu(fin(dn * acc.x) + gcnbf[q*4+0]);
    o.y = lrelu(fin(dn * acc.y) + gcnbf[q*4+1]);
    o.z = lrelu(fin(dn * acc.z) + gcnbf[q*4+2]);
    o.w = lrelu(fin(dn * acc.w) + gcnbf[q*4+3]);
    *reinterpret_cast<float4*>(h + (size_t)n * HID + q * 4) = o;
}

// ---------------- CSR gather, final layer + heads ----------------
__global__ __launch_bounds__(256) void k_gather_final(const unsigned* __restrict__ rowptr,
                                                      const unsigned* __restrict__ deg,
                                                      const unsigned* __restrict__ csr,
                                                      const float* __restrict__ y,
                                                      const float* __restrict__ dinv,
                                                      const float* __restrict__ gcnbf,
                                                      const float* __restrict__ post,
                                                      const int* __restrict__ flags,
                                                      void* __restrict__ out, int N) {
    int tid = blockIdx.x * 256 + threadIdx.x;
    if (tid >= N * 4) return;
    int n = tid >> 2, q = tid & 3;
    unsigned end = rowptr[n];
    unsigned start = end - deg[n];
    float4 acc = *reinterpret_cast<const float4*>(y + (size_t)n * HID + q * 4);
    for (unsigned k = start; k < end; ++k) {
        unsigned src = csr[k];
        float4 v = *reinterpret_cast<const float4*>(y + (size_t)src * HID + q * 4);
        acc.x += v.x; acc.y += v.y; acc.z += v.z; acc.w += v.w;
    }
    float dn = dinv[n];
    float v0 = lrelu(fin(dn * acc.x) + gcnbf[q*4+0]);
    float v1 = lrelu(fin(dn * acc.y) + gcnbf[q*4+1]);
    float v2 = lrelu(fin(dn * acc.z) + gcnbf[q*4+2]);
    float v3 = lrelu(fin(dn * acc.w) + gcnbf[q*4+3]);
    float s1 = v0 * post[q*4+0] + v1 * post[q*4+1] + v2 * post[q*4+2] + v3 * post[q*4+3];
    float s2 = v0 * post[17+q*4+0] + v1 * post[17+q*4+1] + v2 * post[17+q*4+2] + v3 * post[17+q*4+3];
    #pragma unroll
    for (int m = 1; m < 4; m <<= 1) {
        s1 += __shfl_xor(s1, m, 64);
        s2 += __shfl_xor(s2, m, 64);
    }
    if (flags[1]) {
        float* ob = (float*)out;
        if (q == 0) ob[n] = s1 + post[16];
        if (q == 1) ob[N + n] = s2 + post[33];
        float4 o; o.x = v0; o.y = v1; o.z = v2; o.w = v3;
        *reinterpret_cast<float4*>(ob + 2 * (size_t)N + (size_t)n * HID + q * 4) = o;
    } else {
        unsigned short* ob = (unsigned short*)out;
        if (q == 0) ob[n] = f2bf(s1 + post[16]);
        if (q == 1) ob[N + n] = f2bf(s2 + post[33]);
        uint2 u; u.x = pk2(v0, v1); u.y = pk2(v2, v3);
        *reinterpret_cast<uint2*>(ob + 2 * (size_t)N + (size_t)n * HID + q * 4) = u;
    }
}

// ================= fallback (atomic) path kernels =================
__global__ void k_xw(const float* __restrict__ h, const float* __restrict__ W,
                     const float* __restrict__ dinv, const int* __restrict__ flags,
                     void* __restrict__ xw, float* __restrict__ hacc, int N) {
    int n = blockIdx.x * 256 + threadIdx.x;
    if (n >= N) return;
    float hv[HID];
    const float4* hp = reinterpret_cast<const float4*>(h + (size_t)n * HID);
    #pragma unroll
    for (int q = 0; q < 4; ++q) {
        float4 v = hp[q];
        hv[q*4+0] = v.x; hv[q*4+1] = v.y; hv[q*4+2] = v.z; hv[q*4+3] = v.w;
    }
    float dn = dinv[n];
    float sl = dn * dn;
    float o[HID];
    #pragma unroll
    for (int i = 0; i < HID; ++i) {
        float s = 0.f;
        #pragma unroll
        for (int j = 0; j < HID; ++j) s += W[i * HID + j] * hv[j];
        o[i] = s;
    }
    if (flags[1]) {
        float4* xp = reinterpret_cast<float4*>((float*)xw + (size_t)n * HID);
        #pragma unroll
        for (int q = 0; q < 4; ++q) {
            float4 v; v.x = o[q*4+0]; v.y = o[q*4+1]; v.z = o[q*4+2]; v.w = o[q*4+3];
            xp[q] = v;
        }
    } else {
        uint4* xp = reinterpret_cast<uint4*>((unsigned short*)xw + (size_t)n * HID);
        xp[0] = pack8(o);
        xp[1] = pack8(o + 8);
    }
    float4* ap = reinterpret_cast<float4*>(hacc + (size_t)n * HID);
    #pragma unroll
    for (int q = 0; q < 4; ++q) {
        float4 va;
        va.x = o[q*4+0]*sl; va.y = o[q*4+1]*sl; va.z = o[q*4+2]*sl; va.w = o[q*4+3]*sl;
        ap[q] = va;
    }
}

__global__ __launch_bounds__(256) void k_scatter(const int* __restrict__ ei,
                                                 const int* __restrict__ flags,
                                                 const float* __restrict__ dinv,
                                                 const void* __restrict__ xw,
                                                 float* __restrict__ hacc, int E, int N) {
    int e = blockIdx.x * 256 + threadIdx.x;
    if (e >= E) return;
    int s, d;
    if (flags[0]) { s = ei[2 * (size_t)e]; d = ei[2 * ((size_t)E + e)]; }
    else          { s = ei[e];             d = ei[(size_t)E + e]; }
    if ((unsigned)s >= (unsigned)N || (unsigned)d >= (unsigned)N) return;
    float nrm = dinv[s] * dinv[d];
    float v[HID];
    if (flags[1]) {
        const float4* xr = reinterpret_cast<const float4*>((const float*)xw + (size_t)s * HID);
        #pragma unroll
        for (int q = 0; q < 4; ++q) {
            float4 a = xr[q];
            v[q*4+0] = a.x; v[q*4+1] = a.y; v[q*4+2] = a.z; v[q*4+3] = a.w;
        }
    } else {
        const uint4* xr = reinterpret_cast<const uint4*>((const unsigned short*)xw + (size_t)s * HID);
        unpack8(xr[0], v);
        unpack8(xr[1], v + 8);
    }
    float* out = hacc + (size_t)d * HID;
    #pragma unroll
    for (int j = 0; j < HID; ++j) unsafeAtomicAdd(out + j, v[j] * nrm);
}

__global__ void k_finish(const float* __restrict__ hacc, const float* __restrict__ gcnbf,
                         float* __restrict__ h, int N) {
    int n = blockIdx.x * 256 + threadIdx.x;
    if (n >= N) return;
    const float4* ap = reinterpret_cast<const float4*>(hacc + (size_t)n * HID);
    float4* hp = reinterpret_cast<float4*>(h + (size_t)n * HID);
    #pragma unroll
    for (int q = 0; q < 4; ++q) {
        float4 a = ap[q];
        float4 o;
        o.x = lrelu(fin(a.x) + gcnbf[q*4+0]);
        o.y = lrelu(fin(a.y) + gcnbf[q*4+1]);
        o.z = lrelu(fin(a.z) + gcnbf[q*4+2]);
        o.w = lrelu(fin(a.w) + gcnbf[q*4+3]);
        hp[q] = o;
    }
}

__global__ void k_final(const float* __restrict__ hacc, const float* __restrict__ gcnbf,
                        const float* __restrict__ post, const int* __restrict__ flags,
                        void* __restrict__ out, int N) {
    int n = blockIdx.x * 256 + threadIdx.x;
    if (n >= N) return;
    float v[HID];
    const float4* ap = reinterpret_cast<const float4*>(hacc + (size_t)n * HID);
    #pragma unroll
    for (int q = 0; q < 4; ++q) {
        float4 a = ap[q];
        v[q*4+0] = lrelu(fin(a.x) + gcnbf[q*4+0]);
        v[q*4+1] = lrelu(fin(a.y) + gcnbf[q*4+1]);
        v[q*4+2] = lrelu(fin(a.z) + gcnbf[q*4+2]);
        v[q*4+3] = lrelu(fin(a.w) + gcnbf[q*4+3]);
    }
    float o = post[16], an = post[33];
    #pragma unroll
    for (int j = 0; j < HID; ++j) {
        o += v[j] * post[j];
        an += v[j] * post[17 + j];
    }
    if (flags[1]) {
        float* ob = (float*)out;
        ob[n] = o;
        ob[N + n] = an;
        float* hr = ob + 2 * (size_t)N + (size_t)n * HID;
        #pragma unroll
        for (int j = 0; j < HID; ++j) hr[j] = v[j];
    } else {
        unsigned short* ob = (unsigned short*)out;
        ob[n] = f2bf(o);
        ob[N + n] = f2bf(an);
        uint4* hr = reinterpret_cast<uint4*>(ob + 2 * (size_t)N + (size_t)n * HID);
        hr[0] = pack8(v);
        hr[1] = pack8(v + 8);
    }
}

extern "C" void kernel_launch(void* const* d_in, const int* in_sizes, int n_in,
                              void* d_out, int out_size, void* d_ws, size_t ws_size,
                              hipStream_t stream) {
    const void* x    = d_in[0];
    const int*  ei   = (const int*)d_in[1];
    const void* p1W  = d_in[2];
    const void* p1b  = d_in[3];
    const void* p2W  = d_in[4];
    const void* p2b  = d_in[5];
    const void* bih  = d_in[6];
    const void* bhh  = d_in[7];
    const void* wtW  = d_in[8];
    const void* wtb  = d_in[9];
    const void* gcnb = d_in[10];
    const void* po1W = d_in[11];
    const void* po1b = d_in[12];
    const void* poaW = d_in[13];
    const void* poab = d_in[14];

    const int N = in_sizes[0] / IN_DIM;   // 100000
    const int E = in_sizes[1] / 2;        // 3200000

    float* ws = (float*)d_ws;
    float* w1f   = ws + OFF_W1F;
    float* b1f   = ws + OFF_B1F;
    float* w2t   = ws + OFF_W2T;
    float* b2f   = ws + OFF_B2F;
    float* hw    = ws + OFF_HW;
    float* gcnbf = ws + OFF_GCNB;
    float* post  = ws + OFF_POST;
    int*   flags = (int*)(ws + OFF_FLAGS);
    unsigned* bsum = (unsigned*)(ws + OFF_BSUM);
    unsigned* bpre = (unsigned*)(ws + OFF_BPRE);

    const int nb_nodes = (N + 255) / 256;
    const int nb_edges = (E + 255) / 256;
    const int nb_n4    = (N * 4 + 255) / 256;
    const int NB       = (N + 1023) / 1024;

    size_t req_csr = ((size_t)OFF_A0 + 35 * (size_t)N + (size_t)E + 64) * 4;
    size_t req_fb  = ((size_t)OFF_A0 + 33 * (size_t)N + 64) * 4;

    if (ws_size >= req_csr && NB <= 128) {
        // ================= CSR (pull) path =================
        unsigned* deg    = (unsigned*)(ws + OFF_A0);
        unsigned* rowptr = deg + N;
        float*    dinv   = (float*)(rowptr + N);
        unsigned* csr    = (unsigned*)(dinv + N);
        float*    y      = (float*)(csr + E);
        float*    h      = y + (size_t)N * HID;

        hipMemsetAsync(deg, 0, (size_t)N * 4, stream);
        k_detect<<<1, 64, 0, stream>>>((const unsigned short*)x, ei, flags);
        k_prep_small<<<1, 256, 0, stream>>>(bih, bhh, wtW, wtb, po1W, po1b, poaW, poab,
                                            flags, hw, post);
        k_convert<<<128, 256, 0, stream>>>(p1W, p1b, p2W, p2b, gcnb, flags,
                                           w1f, b1f, w2t, b2f, gcnbf);
        k_deg<<<nb_edges, 256, 0, stream>>>(ei, flags, deg, E, N);
        k_dinv2<<<nb_nodes, 256, 0, stream>>>(deg, dinv, N);
        k_scan_block<<<NB, 1024, 0, stream>>>(deg, bsum, N);
        k_scan_top<<<1, 128, 0, stream>>>(bsum, bpre, NB);
        k_scan_final<<<NB, 1024, 0, stream>>>(deg, bpre, rowptr, N);
        k_fill<<<nb_edges, 256, 0, stream>>>(ei, flags, rowptr, csr, E, N);
        k_pre<<<nb_nodes, 256, 0, stream>>>(x, w1f, b1f, w2t, b2f, flags, h, N);

        k_xw_y<<<nb_nodes, 256, 0, stream>>>(h, hw + 0, dinv, y, N);
        k_gather<<<nb_n4, 256, 0, stream>>>(rowptr, deg, csr, y, dinv, gcnbf + 0, h, N);
        k_xw_y<<<nb_nodes, 256, 0, stream>>>(h, hw + 256, dinv, y, N);
        k_gather_final<<<nb_n4, 256, 0, stream>>>(rowptr, deg, csr, y, dinv, gcnbf + 16,
                                                  post, flags, d_out, N);
    } else if (ws_size >= req_fb) {
        // ================= fallback (atomic) path =================
        float* degdinv = ws + OFF_A0;
        float* hacc    = degdinv + N;
        float* h       = hacc + (size_t)N * HID;
        void*  xw      = d_out;

        hipMemsetAsync(degdinv, 0, (size_t)N * 4, stream);
        k_detect<<<1, 64, 0, stream>>>((const unsigned short*)x, ei, flags);
        k_prep_small<<<1, 256, 0, stream>>>(bih, bhh, wtW, wtb, po1W, po1b, poaW, poab,
                                            flags, hw, post);
        k_convert<<<128, 256, 0, stream>>>(p1W, p1b, p2W, p2b, gcnb, flags,
                                           w1f, b1f, w2t, b2f, gcnbf);
        k_deg<<<nb_edges, 256, 0, stream>>>(ei, flags, (unsigned*)degdinv, E, N);
        k_dinv<<<nb_nodes, 256, 0, stream>>>(degdinv, N);
        k_pre<<<nb_nodes, 256, 0, stream>>>(x, w1f, b1f, w2t, b2f, flags, h, N);
        for (int l = 0; l < 2; ++l) {
            k_xw<<<nb_nodes, 256, 0, stream>>>(h, hw + l * 256, degdinv, flags, xw, hacc, N);
            k_scatter<<<nb_edges, 256, 0, stream>>>(ei, flags, degdinv, xw, hacc, E, N);
            if (l == 0) k_finish<<<nb_nodes, 256, 0, stream>>>(hacc, gcnbf + 0, h, N);
            else        k_final<<<nb_nodes, 256, 0, stream>>>(hacc, gcnbf + 16, post, flags, d_out, N);
        }
    } else {
        float f = 256.0f + (float)(ws_size >> 20);
        unsigned uv; __builtin_memcpy(&uv, &f, 4);
        int words = out_size / 2;
        k_sentinel<<<(words + 255) / 256, 256, 0, stream>>>((unsigned*)d_out, words, uv);
    }
}